// Round 1
// baseline (301.831 us; speedup 1.0000x reference)
//
#include <hip/hip_runtime.h>
#include <hip/hip_bf16.h>

// Shapes (fixed by the reference): B=2, S=2048, E=1024, H=16, D=64
// d_out layout: out[4194304] fp32 | k[4194304] fp32 [B,H,S,D] | v[4194304] fp32
// Workspace (~42 MB used): x_bf | wT1 | wT2 | q_bf | k_bf | v_bf ; o_bf aliases x_bf.

typedef __attribute__((ext_vector_type(4))) float f32x4;
typedef __attribute__((ext_vector_type(8))) short s16x8;

__device__ __forceinline__ short f2bf(float f) {
    union { float f; unsigned u; } x{f};
    unsigned r = x.u + 0x7fff + ((x.u >> 16) & 1);
    return (short)(r >> 16);
}

__device__ __forceinline__ void gload_lds16(const void* g, void* l) {
    __builtin_amdgcn_global_load_lds(
        (const __attribute__((address_space(1))) void*)g,
        (__attribute__((address_space(3))) void*)l, 16, 0, 0);
}

// ---------------- pre-pass kernels ----------------

__global__ __launch_bounds__(256) void convert_f32_bf16(const float* __restrict__ in,
                                                        short* __restrict__ out, int n) {
    int i = (blockIdx.x * 256 + threadIdx.x) * 8;
    if (i + 7 < n) {
        f32x4 a = *(const f32x4*)&in[i];
        f32x4 b = *(const f32x4*)&in[i + 4];
        s16x8 o;
        #pragma unroll
        for (int j = 0; j < 4; ++j) o[j] = f2bf(a[j]);
        #pragma unroll
        for (int j = 0; j < 4; ++j) o[j + 4] = f2bf(b[j]);
        *(s16x8*)&out[i] = o;
    }
}

// in: [K][N] fp32 row-major -> out: [N][K] bf16 row-major
__global__ __launch_bounds__(256) void transpose_conv(const float* __restrict__ in,
                                                      short* __restrict__ out, int K, int N) {
    __shared__ float tile[32][33];
    int tx = threadIdx.x, ty = threadIdx.y;  // 32 x 8
    int n0 = blockIdx.x * 32, k0 = blockIdx.y * 32;
    #pragma unroll
    for (int r = 0; r < 4; ++r)
        tile[ty + r * 8][tx] = in[(long)(k0 + ty + r * 8) * N + n0 + tx];
    __syncthreads();
    #pragma unroll
    for (int r = 0; r < 4; ++r)
        out[(long)(n0 + ty + r * 8) * K + k0 + tx] = f2bf(tile[tx][ty + r * 8]);
}

// ---------------- GEMM (m97-style: 128x128 tile, BK=32, global_load_lds) ----------------
// A: [M][K] bf16, Bt: [N][K] bf16.  MODE 1: qkv epilogue. MODE 2: plain bias epilogue.

template <int MODE>
__global__ __launch_bounds__(256) void gemm_bf16(
    const short* __restrict__ A, const short* __restrict__ Bt,
    const float* __restrict__ bias, int M, int N, int K,
    float* __restrict__ outf,
    short* __restrict__ qbf, short* __restrict__ kbf, short* __restrict__ vbf,
    float* __restrict__ kout, float* __restrict__ vout) {
    __shared__ __align__(16) short As[128 * 32];
    __shared__ __align__(16) short Bs[128 * 32];
    const int tid = threadIdx.x;
    const int l = tid & 63, w = tid >> 6;
    const int lr = l >> 4, lc = l & 15;
    const int wm = w >> 1, wn = w & 1;
    const int m0 = blockIdx.y * 128, n0 = blockIdx.x * 128;

    f32x4 acc[4][4] = {};
    const int c0 = tid, c1 = tid + 256;  // 16B chunks; chunk c -> row c>>2, seg c&3

    for (int kb = 0; kb < K; kb += 32) {
        __syncthreads();
        gload_lds16(A + (long)(m0 + (c0 >> 2)) * K + kb + (c0 & 3) * 8, As + c0 * 8);
        gload_lds16(A + (long)(m0 + (c1 >> 2)) * K + kb + (c1 & 3) * 8, As + c1 * 8);
        gload_lds16(Bt + (long)(n0 + (c0 >> 2)) * K + kb + (c0 & 3) * 8, Bs + c0 * 8);
        gload_lds16(Bt + (long)(n0 + (c1 >> 2)) * K + kb + (c1 & 3) * 8, Bs + c1 * 8);
        __syncthreads();
        s16x8 af[4], bfr[4];
        #pragma unroll
        for (int mi = 0; mi < 4; ++mi)
            af[mi] = *(const s16x8*)&As[(wm * 64 + mi * 16 + lc) * 32 + lr * 8];
        #pragma unroll
        for (int ni = 0; ni < 4; ++ni)
            bfr[ni] = *(const s16x8*)&Bs[(wn * 64 + ni * 16 + lc) * 32 + lr * 8];
        #pragma unroll
        for (int mi = 0; mi < 4; ++mi)
            #pragma unroll
            for (int ni = 0; ni < 4; ++ni)
                acc[mi][ni] = __builtin_amdgcn_mfma_f32_16x16x32_bf16(
                    af[mi], bfr[ni], acc[mi][ni], 0, 0, 0);
    }

    #pragma unroll
    for (int mi = 0; mi < 4; ++mi) {
        #pragma unroll
        for (int ni = 0; ni < 4; ++ni) {
            int col = n0 + wn * 64 + ni * 16 + lc;
            float bv = bias[col];
            if (MODE == 1) {
                int sec = col >> 10, rem = col & 1023;
                int h = rem >> 6, d = rem & 63;
                #pragma unroll
                for (int i = 0; i < 4; ++i) {
                    int row = m0 + wm * 64 + mi * 16 + lr * 4 + i;
                    float val = acc[mi][ni][i] + bv;
                    int b = row >> 11, s = row & 2047;
                    long idx = ((long)((b << 4) + h) * 2048 + s) * 64 + d;
                    if (sec == 0) {
                        qbf[idx] = f2bf(val * 0.125f);  // bake in 1/sqrt(64)
                    } else if (sec == 1) {
                        kout[idx] = val; kbf[idx] = f2bf(val);
                    } else {
                        vout[idx] = val; vbf[idx] = f2bf(val);
                    }
                }
            } else {
                #pragma unroll
                for (int i = 0; i < 4; ++i) {
                    int row = m0 + wm * 64 + mi * 16 + lr * 4 + i;
                    outf[(long)row * N + col] = acc[mi][ni][i] + bv;
                }
            }
        }
    }
}

// ---------------- flash attention ----------------
// grid: B*H*(S/64) = 1024 blocks, 256 threads (4 waves). Wave w: q rows qt*64+w*16 .. +15.
__global__ __launch_bounds__(256) void attn_kernel(const short* __restrict__ qbf,
                                                   const short* __restrict__ kbf,
                                                   const short* __restrict__ vbf,
                                                   short* __restrict__ obf) {
    const int bx = blockIdx.x;
    const int qt = bx & 31;       // q-tile (64 rows)
    const int bh = bx >> 5;       // b*16+h
    const int tid = threadIdx.x;
    const int w = tid >> 6, l = tid & 63;
    const int lr = l >> 4, lc = l & 15;
    const long base = (long)bh * 2048 * 64;
    const int q0w = qt * 64 + w * 16;

    __shared__ __align__(16) short Vt[64][72];       // V^T tile, padded
    __shared__ __align__(16) short P[4][16][72];     // per-wave P, padded

    s16x8 qf[2];
    qf[0] = *(const s16x8*)&qbf[base + (long)(q0w + lc) * 64 + lr * 8];
    qf[1] = *(const s16x8*)&qbf[base + (long)(q0w + lc) * 64 + lr * 8 + 32];

    float m_[4], lsum[4];
    f32x4 Oacc[4] = {};
    #pragma unroll
    for (int i = 0; i < 4; ++i) { m_[i] = -INFINITY; lsum[i] = 0.f; }

    const int nkt = qt + 1;
    for (int kt = 0; kt < nkt; ++kt) {
        const int k0 = kt * 64;
        __syncthreads();  // protect Vt/P from previous iteration's reads
        // stage V^T
        {
            int r0 = tid >> 3, c8 = tid & 7;
            #pragma unroll
            for (int rr = 0; rr < 2; ++rr) {
                int r = r0 + rr * 32;
                s16x8 v = *(const s16x8*)&vbf[base + (long)(k0 + r) * 64 + c8 * 8];
                #pragma unroll
                for (int j = 0; j < 8; ++j) Vt[c8 * 8 + j][r] = v[j];
            }
        }
        __syncthreads();

        // QK^T: scores tile 16q x 64k per wave
        f32x4 sc[4];
        #pragma unroll
        for (int kk = 0; kk < 4; ++kk) {
            s16x8 kf0 = *(const s16x8*)&kbf[base + (long)(k0 + kk * 16 + lc) * 64 + lr * 8];
            s16x8 kf1 = *(const s16x8*)&kbf[base + (long)(k0 + kk * 16 + lc) * 64 + lr * 8 + 32];
            f32x4 z = {};
            z = __builtin_amdgcn_mfma_f32_16x16x32_bf16(qf[0], kf0, z, 0, 0, 0);
            z = __builtin_amdgcn_mfma_f32_16x16x32_bf16(qf[1], kf1, z, 0, 0, 0);
            sc[kk] = z;
        }
        if (kt == qt) {  // diagonal tile: causal mask
            #pragma unroll
            for (int kk = 0; kk < 4; ++kk)
                #pragma unroll
                for (int i = 0; i < 4; ++i) {
                    int kpos = k0 + kk * 16 + lc;
                    int q = q0w + lr * 4 + i;
                    if (kpos > q) sc[kk][i] = -INFINITY;
                }
        }
        // online softmax
        float mx[4];
        #pragma unroll
        for (int i = 0; i < 4; ++i)
            mx[i] = fmaxf(fmaxf(sc[0][i], sc[1][i]), fmaxf(sc[2][i], sc[3][i]));
        #pragma unroll
        for (int off = 1; off < 16; off <<= 1)
            #pragma unroll
            for (int i = 0; i < 4; ++i) mx[i] = fmaxf(mx[i], __shfl_xor(mx[i], off));
        float fac[4];
        #pragma unroll
        for (int i = 0; i < 4; ++i) {
            float mn = fmaxf(m_[i], mx[i]);
            fac[i] = __expf(m_[i] - mn);
            m_[i] = mn;
        }
        float rs[4] = {0.f, 0.f, 0.f, 0.f};
        #pragma unroll
        for (int kk = 0; kk < 4; ++kk)
            #pragma unroll
            for (int i = 0; i < 4; ++i) {
                float p = __expf(sc[kk][i] - m_[i]);
                rs[i] += p;
                P[w][lr * 4 + i][kk * 16 + lc] = f2bf(p);
            }
        #pragma unroll
        for (int off = 1; off < 16; off <<= 1)
            #pragma unroll
            for (int i = 0; i < 4; ++i) rs[i] += __shfl_xor(rs[i], off);
        #pragma unroll
        for (int i = 0; i < 4; ++i) lsum[i] = lsum[i] * fac[i] + rs[i];
        #pragma unroll
        for (int dt = 0; dt < 4; ++dt)
            #pragma unroll
            for (int i = 0; i < 4; ++i) Oacc[dt][i] *= fac[i];
        __syncthreads();  // P visible (and ordered) for PV reads

        // PV: O += P @ V
        #pragma unroll
        for (int kk2 = 0; kk2 < 2; ++kk2) {
            s16x8 pf = *(const s16x8*)&P[w][lc][lr * 8 + kk2 * 32];
            #pragma unroll
            for (int dt = 0; dt < 4; ++dt) {
                s16x8 vf = *(const s16x8*)&Vt[dt * 16 + lc][lr * 8 + kk2 * 32];
                Oacc[dt] = __builtin_amdgcn_mfma_f32_16x16x32_bf16(pf, vf, Oacc[dt], 0, 0, 0);
            }
        }
    }

    // epilogue: O /= lsum, write to o_bf [B,S,H*D]
    const int b = bh >> 4, h = bh & 15;
    float inv[4];
    #pragma unroll
    for (int i = 0; i < 4; ++i) inv[i] = 1.0f / lsum[i];
    #pragma unroll
    for (int dt = 0; dt < 4; ++dt)
        #pragma unroll
        for (int i = 0; i < 4; ++i) {
            int qrow = q0w + lr * 4 + i;
            obf[(long)(b * 2048 + qrow) * 1024 + h * 64 + dt * 16 + lc] =
                f2bf(Oacc[dt][i] * inv[i]);
        }
}

// ---------------- launch ----------------

extern "C" void kernel_launch(void* const* d_in, const int* in_sizes, int n_in,
                              void* d_out, int out_size, void* d_ws, size_t ws_size,
                              hipStream_t stream) {
    const float* x = (const float*)d_in[0];
    const float* qkv_w = (const float*)d_in[1];
    const float* qkv_b = (const float*)d_in[2];
    const float* proj_w = (const float*)d_in[3];
    const float* proj_b = (const float*)d_in[4];

    float* out = (float*)d_out;
    float* kout = out + 4194304;
    float* vout = out + 8388608;

    short* x_bf = (short*)d_ws;           // 4194304 shorts
    short* wT1 = x_bf + 4194304;          // 3145728
    short* wT2 = wT1 + 3145728;           // 1048576
    short* q_bf = wT2 + 1048576;          // 4194304
    short* k_bf = q_bf + 4194304;         // 4194304
    short* v_bf = k_bf + 4194304;         // 4194304
    short* o_bf = x_bf;                   // alias: x_bf dead after GEMM1

    convert_f32_bf16<<<2048, 256, 0, stream>>>(x, x_bf, 4194304);
    transpose_conv<<<dim3(96, 32), dim3(32, 8), 0, stream>>>(qkv_w, wT1, 1024, 3072);
    transpose_conv<<<dim3(32, 32), dim3(32, 8), 0, stream>>>(proj_w, wT2, 1024, 1024);

    gemm_bf16<1><<<dim3(24, 32), 256, 0, stream>>>(x_bf, wT1, qkv_b, 4096, 3072, 1024,
                                                   nullptr, q_bf, k_bf, v_bf, kout, vout);

    attn_kernel<<<1024, 256, 0, stream>>>(q_bf, k_bf, v_bf, o_bf);

    gemm_bf16<2><<<dim3(8, 32), 256, 0, stream>>>(o_bf, wT2, proj_b, 4096, 1024, 1024,
                                                  out, nullptr, nullptr, nullptr, nullptr, nullptr);
}

// Round 2
// 202.921 us; speedup vs baseline: 1.4874x; 1.4874x over previous
//
#include <hip/hip_runtime.h>
#include <hip/hip_bf16.h>

// Shapes (fixed): B=2, S=2048, E=1024, H=16, D=64
// d_out: out[4194304] fp32 | k[4194304] fp32 [B,H,S,D] | v[4194304] fp32 [B,H,S,D]
// ws: x_bf | wT1 | wT2 | q_bf | k_bf | vT_bf ; o_bf aliases x_bf.

typedef __attribute__((ext_vector_type(4))) float f32x4;
typedef __attribute__((ext_vector_type(8))) short s16x8;
typedef __attribute__((ext_vector_type(4))) short s16x4;

__device__ __forceinline__ short f2bf(float f) {
    union { float f; unsigned u; } x{f};
    unsigned r = x.u + 0x7fff + ((x.u >> 16) & 1);
    return (short)(r >> 16);
}

__device__ __forceinline__ void gload_lds16(const void* g, void* l) {
    __builtin_amdgcn_global_load_lds(
        (const __attribute__((address_space(1))) void*)g,
        (__attribute__((address_space(3))) void*)l, 16, 0, 0);
}

// ---------------- pre-pass kernels ----------------

__global__ __launch_bounds__(256) void convert_f32_bf16(const float* __restrict__ in,
                                                        short* __restrict__ out, int n) {
    int i = (blockIdx.x * 256 + threadIdx.x) * 8;
    if (i + 7 < n) {
        f32x4 a = *(const f32x4*)&in[i];
        f32x4 b = *(const f32x4*)&in[i + 4];
        s16x8 o;
        #pragma unroll
        for (int j = 0; j < 4; ++j) o[j] = f2bf(a[j]);
        #pragma unroll
        for (int j = 0; j < 4; ++j) o[j + 4] = f2bf(b[j]);
        *(s16x8*)&out[i] = o;
    }
}

// in: [K][N] fp32 row-major -> out: [N][K] bf16 row-major
__global__ __launch_bounds__(256) void transpose_conv(const float* __restrict__ in,
                                                      short* __restrict__ out, int K, int N) {
    __shared__ float tile[32][33];
    int tx = threadIdx.x, ty = threadIdx.y;  // 32 x 8
    int n0 = blockIdx.x * 32, k0 = blockIdx.y * 32;
    #pragma unroll
    for (int r = 0; r < 4; ++r)
        tile[ty + r * 8][tx] = in[(long)(k0 + ty + r * 8) * N + n0 + tx];
    __syncthreads();
    #pragma unroll
    for (int r = 0; r < 4; ++r)
        out[(long)(n0 + ty + r * 8) * K + k0 + tx] = f2bf(tile[tx][ty + r * 8]);
}

// ---------------- GEMM (m97-style: 128x128 tile, BK=32, global_load_lds) ----------------
// A: [M][K] bf16, Bt: [N][K] bf16.  MODE 1: qkv epilogue. MODE 2: plain bias epilogue.

template <int MODE>
__global__ __launch_bounds__(256) void gemm_bf16(
    const short* __restrict__ A, const short* __restrict__ Bt,
    const float* __restrict__ bias, int M, int N, int K,
    float* __restrict__ outf,
    short* __restrict__ qbf, short* __restrict__ kbf, short* __restrict__ vbfT,
    float* __restrict__ kout, float* __restrict__ vout) {
    __shared__ __align__(16) short As[128 * 32];
    __shared__ __align__(16) short Bs[128 * 32];
    const int tid = threadIdx.x;
    const int l = tid & 63, w = tid >> 6;
    const int lr = l >> 4, lc = l & 15;
    const int wm = w >> 1, wn = w & 1;
    const int m0 = blockIdx.y * 128, n0 = blockIdx.x * 128;

    f32x4 acc[4][4] = {};
    const int c0 = tid, c1 = tid + 256;  // 16B chunks; chunk c -> row c>>2, seg c&3

    for (int kb = 0; kb < K; kb += 32) {
        __syncthreads();
        gload_lds16(A + (long)(m0 + (c0 >> 2)) * K + kb + (c0 & 3) * 8, As + c0 * 8);
        gload_lds16(A + (long)(m0 + (c1 >> 2)) * K + kb + (c1 & 3) * 8, As + c1 * 8);
        gload_lds16(Bt + (long)(n0 + (c0 >> 2)) * K + kb + (c0 & 3) * 8, Bs + c0 * 8);
        gload_lds16(Bt + (long)(n0 + (c1 >> 2)) * K + kb + (c1 & 3) * 8, Bs + c1 * 8);
        __syncthreads();
        s16x8 af[4], bfr[4];
        #pragma unroll
        for (int mi = 0; mi < 4; ++mi)
            af[mi] = *(const s16x8*)&As[(wm * 64 + mi * 16 + lc) * 32 + lr * 8];
        #pragma unroll
        for (int ni = 0; ni < 4; ++ni)
            bfr[ni] = *(const s16x8*)&Bs[(wn * 64 + ni * 16 + lc) * 32 + lr * 8];
        #pragma unroll
        for (int mi = 0; mi < 4; ++mi)
            #pragma unroll
            for (int ni = 0; ni < 4; ++ni)
                acc[mi][ni] = __builtin_amdgcn_mfma_f32_16x16x32_bf16(
                    af[mi], bfr[ni], acc[mi][ni], 0, 0, 0);
    }

    #pragma unroll
    for (int mi = 0; mi < 4; ++mi) {
        #pragma unroll
        for (int ni = 0; ni < 4; ++ni) {
            int col = n0 + wn * 64 + ni * 16 + lc;
            float bv = bias[col];
            if (MODE == 1) {
                int sec = col >> 10, rem = col & 1023;
                int h = rem >> 6, d = rem & 63;
                int row0 = m0 + wm * 64 + mi * 16 + lr * 4;
                int b = row0 >> 11, s0 = row0 & 2047;
                long idxSD = ((long)((b << 4) + h) * 2048 + s0) * 64 + d;
                if (sec == 0) {
                    #pragma unroll
                    for (int i = 0; i < 4; ++i) {
                        float val = acc[mi][ni][i] + bv;
                        // bake attn scale 1/8 and log2(e) for exp2-domain softmax
                        qbf[idxSD + (long)i * 64] = f2bf(val * 0.1803368801111244f);
                    }
                } else if (sec == 1) {
                    #pragma unroll
                    for (int i = 0; i < 4; ++i) {
                        float val = acc[mi][ni][i] + bv;
                        kout[idxSD + (long)i * 64] = val;
                        kbf[idxSD + (long)i * 64] = f2bf(val);
                    }
                } else {
                    s16x4 pk;
                    #pragma unroll
                    for (int i = 0; i < 4; ++i) {
                        float val = acc[mi][ni][i] + bv;
                        vout[idxSD + (long)i * 64] = val;
                        pk[i] = f2bf(val);
                    }
                    // transposed bf16 copy: [B,H,D,S], s-contiguous -> 8B packed store
                    *(s16x4*)&vbfT[((long)((b << 4) + h) * 64 + d) * 2048 + s0] = pk;
                }
            } else {
                #pragma unroll
                for (int i = 0; i < 4; ++i) {
                    int row = m0 + wm * 64 + mi * 16 + lr * 4 + i;
                    outf[(long)row * N + col] = acc[mi][ni][i] + bv;
                }
            }
        }
    }
}

// ---------------- flash attention ----------------
// grid: B*H*16 = 512 blocks, 512 threads (8 waves). No __syncthreads().
// waves 0-3 -> q-tile p (rows p*64 + w*16), waves 4-7 -> q-tile 31-p. Work = 33 tiles/block.
__global__ __launch_bounds__(512, 4) void attn_kernel(const short* __restrict__ qbf,
                                                      const short* __restrict__ kbf,
                                                      const short* __restrict__ vbfT,
                                                      short* __restrict__ obf) {
    const int px = blockIdx.x;
    const int bh = px >> 4, pr = px & 15;
    const int tid = threadIdx.x;
    const int wv = tid >> 6, l = tid & 63;
    const int lr = l >> 4, lc = l & 15;
    const int qt = (wv < 4) ? pr : (31 - pr);
    const int q0w = qt * 64 + (wv & 3) * 16;
    const long baseSD = (long)bh * 2048 * 64;   // q,k: [S][64]
    const long baseDS = (long)bh * 64 * 2048;   // vT:  [64][S]

    __shared__ short P[8][16][76];  // per-wave P transpose buffer (stride 76: conflict-free writes)

    s16x8 qf0 = *(const s16x8*)&qbf[baseSD + (long)(q0w + lc) * 64 + lr * 8];
    s16x8 qf1 = *(const s16x8*)&qbf[baseSD + (long)(q0w + lc) * 64 + lr * 8 + 32];

    float m_[4], lsum[4];
    f32x4 Oacc[4] = {};
    #pragma unroll
    for (int i = 0; i < 4; ++i) { m_[i] = -INFINITY; lsum[i] = 0.f; }

    for (int kt = 0; kt <= qt; ++kt) {
        const int k0 = kt * 64;
        // issue V^T fragment loads early (independent; hide L2 latency under QK+softmax)
        s16x8 vfr[2][4];
        #pragma unroll
        for (int kk2 = 0; kk2 < 2; ++kk2)
            #pragma unroll
            for (int dt = 0; dt < 4; ++dt)
                vfr[kk2][dt] = *(const s16x8*)&vbfT[baseDS + (long)(dt * 16 + lc) * 2048 +
                                                   k0 + kk2 * 32 + lr * 8];
        // QK^T: 16q x 64k
        f32x4 sc[4];
        #pragma unroll
        for (int kk = 0; kk < 4; ++kk) {
            s16x8 kf0 = *(const s16x8*)&kbf[baseSD + (long)(k0 + kk * 16 + lc) * 64 + lr * 8];
            s16x8 kf1 = *(const s16x8*)&kbf[baseSD + (long)(k0 + kk * 16 + lc) * 64 + lr * 8 + 32];
            f32x4 z = {};
            z = __builtin_amdgcn_mfma_f32_16x16x32_bf16(qf0, kf0, z, 0, 0, 0);
            z = __builtin_amdgcn_mfma_f32_16x16x32_bf16(qf1, kf1, z, 0, 0, 0);
            sc[kk] = z;
        }
        if (kt == qt) {  // causal mask on diagonal tile
            #pragma unroll
            for (int kk = 0; kk < 4; ++kk)
                #pragma unroll
                for (int i = 0; i < 4; ++i)
                    if (k0 + kk * 16 + lc > q0w + lr * 4 + i) sc[kk][i] = -INFINITY;
        }
        // online softmax (exp2 domain; scale baked into q)
        float mx[4];
        #pragma unroll
        for (int i = 0; i < 4; ++i)
            mx[i] = fmaxf(fmaxf(sc[0][i], sc[1][i]), fmaxf(sc[2][i], sc[3][i]));
        #pragma unroll
        for (int off = 1; off < 16; off <<= 1)
            #pragma unroll
            for (int i = 0; i < 4; ++i) mx[i] = fmaxf(mx[i], __shfl_xor(mx[i], off));
        float fac[4];
        #pragma unroll
        for (int i = 0; i < 4; ++i) {
            float mn = fmaxf(m_[i], mx[i]);
            fac[i] = __builtin_amdgcn_exp2f(m_[i] - mn);
            m_[i] = mn;
        }
        float rs[4] = {0.f, 0.f, 0.f, 0.f};
        #pragma unroll
        for (int kk = 0; kk < 4; ++kk)
            #pragma unroll
            for (int i = 0; i < 4; ++i) {
                float p = __builtin_amdgcn_exp2f(sc[kk][i] - m_[i]);
                rs[i] += p;
                P[wv][lr * 4 + i][kk * 16 + lc] = f2bf(p);
            }
        #pragma unroll
        for (int off = 1; off < 16; off <<= 1)
            #pragma unroll
            for (int i = 0; i < 4; ++i) rs[i] += __shfl_xor(rs[i], off);
        #pragma unroll
        for (int i = 0; i < 4; ++i) lsum[i] = lsum[i] * fac[i] + rs[i];
        #pragma unroll
        for (int dt = 0; dt < 4; ++dt)
            #pragma unroll
            for (int i = 0; i < 4; ++i) Oacc[dt][i] *= fac[i];

        // PV: O += P @ V   (per-wave LDS; same-wave DS ordering, no barrier)
        #pragma unroll
        for (int kk2 = 0; kk2 < 2; ++kk2) {
            s16x8 pf = *(const s16x8*)&P[wv][lc][lr * 8 + kk2 * 32];
            #pragma unroll
            for (int dt = 0; dt < 4; ++dt)
                Oacc[dt] = __builtin_amdgcn_mfma_f32_16x16x32_bf16(pf, vfr[kk2][dt],
                                                                   Oacc[dt], 0, 0, 0);
        }
    }

    // epilogue: O /= lsum, write o_bf [B,S,H*D]
    const int b = bh >> 4, h = bh & 15;
    float inv[4];
    #pragma unroll
    for (int i = 0; i < 4; ++i) inv[i] = 1.0f / lsum[i];
    #pragma unroll
    for (int dt = 0; dt < 4; ++dt)
        #pragma unroll
        for (int i = 0; i < 4; ++i) {
            int qrow = q0w + lr * 4 + i;
            obf[(long)(b * 2048 + qrow) * 1024 + h * 64 + dt * 16 + lc] =
                f2bf(Oacc[dt][i] * inv[i]);
        }
}

// ---------------- launch ----------------

extern "C" void kernel_launch(void* const* d_in, const int* in_sizes, int n_in,
                              void* d_out, int out_size, void* d_ws, size_t ws_size,
                              hipStream_t stream) {
    const float* x = (const float*)d_in[0];
    const float* qkv_w = (const float*)d_in[1];
    const float* qkv_b = (const float*)d_in[2];
    const float* proj_w = (const float*)d_in[3];
    const float* proj_b = (const float*)d_in[4];

    float* out = (float*)d_out;
    float* kout = out + 4194304;
    float* vout = out + 8388608;

    short* x_bf = (short*)d_ws;           // 4194304 shorts
    short* wT1 = x_bf + 4194304;          // 3145728
    short* wT2 = wT1 + 3145728;           // 1048576
    short* q_bf = wT2 + 1048576;          // 4194304
    short* k_bf = q_bf + 4194304;         // 4194304
    short* vT_bf = k_bf + 4194304;        // 4194304 ([B,H,D,S])
    short* o_bf = x_bf;                   // alias: x_bf dead after GEMM1

    convert_f32_bf16<<<2048, 256, 0, stream>>>(x, x_bf, 4194304);
    transpose_conv<<<dim3(96, 32), dim3(32, 8), 0, stream>>>(qkv_w, wT1, 1024, 3072);
    transpose_conv<<<dim3(32, 32), dim3(32, 8), 0, stream>>>(proj_w, wT2, 1024, 1024);

    gemm_bf16<1><<<dim3(24, 32), 256, 0, stream>>>(x_bf, wT1, qkv_b, 4096, 3072, 1024,
                                                   nullptr, q_bf, k_bf, vT_bf, kout, vout);

    attn_kernel<<<512, 512, 0, stream>>>(q_bf, k_bf, vT_bf, o_bf);

    gemm_bf16<2><<<dim3(8, 32), 256, 0, stream>>>(o_bf, wT2, proj_b, 4096, 1024, 1024,
                                                  out, nullptr, nullptr, nullptr, nullptr, nullptr);
}

// Round 4
// 202.432 us; speedup vs baseline: 1.4910x; 1.0024x over previous
//
#include <hip/hip_runtime.h>
#include <hip/hip_bf16.h>

// Shapes (fixed): B=2, S=2048, E=1024, H=16, D=64
// d_out: out[4194304] fp32 | k[4194304] fp32 [B,H,S,D] | v[4194304] fp32 [B,H,S,D]
// ws: x_bf | wT1 | wT2 | q_bf | k_bf | vT_bf ; o_bf aliases x_bf.

typedef __attribute__((ext_vector_type(4))) float f32x4;
typedef __attribute__((ext_vector_type(8))) short s16x8;
typedef __attribute__((ext_vector_type(4))) short s16x4;

__device__ __forceinline__ short f2bf(float f) {
    union { float f; unsigned u; } x{f};
    unsigned r = x.u + 0x7fff + ((x.u >> 16) & 1);
    return (short)(r >> 16);
}

__device__ __forceinline__ void gload_lds16(const void* g, void* l) {
    __builtin_amdgcn_global_load_lds(
        (const __attribute__((address_space(1))) void*)g,
        (__attribute__((address_space(3))) void*)l, 16, 0, 0);
}

// ---------------- pre-pass kernels ----------------

__global__ __launch_bounds__(256) void convert_f32_bf16(const float* __restrict__ in,
                                                        short* __restrict__ out, int n) {
    int i = (blockIdx.x * 256 + threadIdx.x) * 8;
    if (i + 7 < n) {
        f32x4 a = *(const f32x4*)&in[i];
        f32x4 b = *(const f32x4*)&in[i + 4];
        s16x8 o;
        #pragma unroll
        for (int j = 0; j < 4; ++j) o[j] = f2bf(a[j]);
        #pragma unroll
        for (int j = 0; j < 4; ++j) o[j + 4] = f2bf(b[j]);
        *(s16x8*)&out[i] = o;
    }
}

// in: [K][N] fp32 row-major -> out: [N][K] bf16 row-major
__global__ __launch_bounds__(256) void transpose_conv(const float* __restrict__ in,
                                                      short* __restrict__ out, int K, int N) {
    __shared__ float tile[32][33];
    int tx = threadIdx.x, ty = threadIdx.y;  // 32 x 8
    int n0 = blockIdx.x * 32, k0 = blockIdx.y * 32;
    #pragma unroll
    for (int r = 0; r < 4; ++r)
        tile[ty + r * 8][tx] = in[(long)(k0 + ty + r * 8) * N + n0 + tx];
    __syncthreads();
    #pragma unroll
    for (int r = 0; r < 4; ++r)
        out[(long)(n0 + ty + r * 8) * K + k0 + tx] = f2bf(tile[tx][ty + r * 8]);
}

// ---------------- GEMM (m97-style: 128x128 tile, BK=32, global_load_lds) ----------------
// A: [M][K] bf16, Bt: [N][K] bf16.  MODE 1: qkv epilogue. MODE 2: plain bias epilogue.

template <int MODE>
__global__ __launch_bounds__(256) void gemm_bf16(
    const short* __restrict__ A, const short* __restrict__ Bt,
    const float* __restrict__ bias, int M, int N, int K,
    float* __restrict__ outf,
    short* __restrict__ qbf, short* __restrict__ kbf, short* __restrict__ vbfT,
    float* __restrict__ kout, float* __restrict__ vout) {
    __shared__ __align__(16) short As[128 * 32];
    __shared__ __align__(16) short Bs[128 * 32];
    const int tid = threadIdx.x;
    const int l = tid & 63, w = tid >> 6;
    const int lr = l >> 4, lc = l & 15;
    const int wm = w >> 1, wn = w & 1;
    const int m0 = blockIdx.y * 128, n0 = blockIdx.x * 128;

    f32x4 acc[4][4] = {};
    const int c0 = tid, c1 = tid + 256;  // 16B chunks; chunk c -> row c>>2, seg c&3

    for (int kb = 0; kb < K; kb += 32) {
        __syncthreads();
        gload_lds16(A + (long)(m0 + (c0 >> 2)) * K + kb + (c0 & 3) * 8, As + c0 * 8);
        gload_lds16(A + (long)(m0 + (c1 >> 2)) * K + kb + (c1 & 3) * 8, As + c1 * 8);
        gload_lds16(Bt + (long)(n0 + (c0 >> 2)) * K + kb + (c0 & 3) * 8, Bs + c0 * 8);
        gload_lds16(Bt + (long)(n0 + (c1 >> 2)) * K + kb + (c1 & 3) * 8, Bs + c1 * 8);
        __syncthreads();
        s16x8 af[4], bfr[4];
        #pragma unroll
        for (int mi = 0; mi < 4; ++mi)
            af[mi] = *(const s16x8*)&As[(wm * 64 + mi * 16 + lc) * 32 + lr * 8];
        #pragma unroll
        for (int ni = 0; ni < 4; ++ni)
            bfr[ni] = *(const s16x8*)&Bs[(wn * 64 + ni * 16 + lc) * 32 + lr * 8];
        #pragma unroll
        for (int mi = 0; mi < 4; ++mi)
            #pragma unroll
            for (int ni = 0; ni < 4; ++ni)
                acc[mi][ni] = __builtin_amdgcn_mfma_f32_16x16x32_bf16(
                    af[mi], bfr[ni], acc[mi][ni], 0, 0, 0);
    }

    #pragma unroll
    for (int mi = 0; mi < 4; ++mi) {
        #pragma unroll
        for (int ni = 0; ni < 4; ++ni) {
            int col = n0 + wn * 64 + ni * 16 + lc;
            float bv = bias[col];
            if (MODE == 1) {
                int sec = col >> 10, rem = col & 1023;
                int h = rem >> 6, d = rem & 63;
                int row0 = m0 + wm * 64 + mi * 16 + lr * 4;
                int b = row0 >> 11, s0 = row0 & 2047;
                long idxSD = ((long)((b << 4) + h) * 2048 + s0) * 64 + d;
                if (sec == 0) {
                    #pragma unroll
                    for (int i = 0; i < 4; ++i) {
                        float val = acc[mi][ni][i] + bv;
                        // bake attn scale 1/8 and log2(e) for exp2-domain softmax
                        qbf[idxSD + (long)i * 64] = f2bf(val * 0.1803368801111244f);
                    }
                } else if (sec == 1) {
                    #pragma unroll
                    for (int i = 0; i < 4; ++i) {
                        float val = acc[mi][ni][i] + bv;
                        kout[idxSD + (long)i * 64] = val;
                        kbf[idxSD + (long)i * 64] = f2bf(val);
                    }
                } else {
                    s16x4 pk;
                    #pragma unroll
                    for (int i = 0; i < 4; ++i) {
                        float val = acc[mi][ni][i] + bv;
                        vout[idxSD + (long)i * 64] = val;
                        pk[i] = f2bf(val);
                    }
                    // transposed bf16 copy: [B,H,D,S], s-contiguous -> 8B packed store
                    *(s16x4*)&vbfT[((long)((b << 4) + h) * 64 + d) * 2048 + s0] = pk;
                }
            } else {
                #pragma unroll
                for (int i = 0; i < 4; ++i) {
                    int row = m0 + wm * 64 + mi * 16 + lr * 4 + i;
                    outf[(long)row * N + col] = acc[mi][ni][i] + bv;
                }
            }
        }
    }
}

// ---------------- flash attention (swapped-operand softmax) ----------------
// grid: B*H*16 = 512 blocks, 512 threads (8 waves). No __syncthreads().
// waves 0-3 -> q-tile pr, waves 4-7 -> q-tile 31-pr. Work = 33 tile-units/block.
// S^T = mfma(K, Q): lane holds col q = lane&15, rows k = (lane>>4)*4+i (+16*kk).
//   -> row state (m_) shared by lanes {lc, lc+16, lc+32, lc+48}: 2-shuffle reduce (xor 16,32).
//   -> lsum kept as per-lane PARTIAL sum (lane's own k-subset); reduced once in epilogue.
// PV = mfma(V^T, P^T): accumulator col q = lane&15 -> rescale factor wave-consistent per lc.
__global__ __launch_bounds__(512, 4) void attn_kernel(const short* __restrict__ qbf,
                                                      const short* __restrict__ kbf,
                                                      const short* __restrict__ vbfT,
                                                      short* __restrict__ obf) {
    const int px = blockIdx.x;
    const int bh = px >> 4, pr = px & 15;
    const int tid = threadIdx.x;
    const int wv = tid >> 6, l = tid & 63;
    const int lr = l >> 4, lc = l & 15;
    const int qt = (wv < 4) ? pr : (31 - pr);
    const int q0w = qt * 64 + (wv & 3) * 16;
    const long baseSD = (long)bh * 2048 * 64;   // q,k: [S][64]
    const long baseDS = (long)bh * 64 * 2048;   // vT:  [64][S]

    __shared__ short P[8][16][76];  // per-wave P^T staging, row = q (stride 76: 0-conflict)

    // Q fragment (B-operand): lane holds col q = q0w+lc, d = lr*8.. (+32 second half)
    s16x8 qf0 = *(const s16x8*)&qbf[baseSD + (long)(q0w + lc) * 64 + lr * 8];
    s16x8 qf1 = *(const s16x8*)&qbf[baseSD + (long)(q0w + lc) * 64 + lr * 8 + 32];

    float m_ = -INFINITY, lsum = 0.f;  // m_: row max (consistent across lr-group); lsum: PARTIAL
    f32x4 Oacc[4] = {};                // O^T: Oacc[dt][i] = O[d=dt*16+lr*4+i][q=lc]

    for (int kt = 0; kt <= qt; ++kt) {
        const int k0 = kt * 64;
        // K fragments (A-operand): lane holds k-row k0+kk*16+lc, d = lr*8..
        s16x8 kf0[4], kf1[4];
        #pragma unroll
        for (int kk = 0; kk < 4; ++kk) {
            kf0[kk] = *(const s16x8*)&kbf[baseSD + (long)(k0 + kk * 16 + lc) * 64 + lr * 8];
            kf1[kk] = *(const s16x8*)&kbf[baseSD + (long)(k0 + kk * 16 + lc) * 64 + lr * 8 + 32];
        }
        // S^T = K @ Q^T
        f32x4 sc[4];
        #pragma unroll
        for (int kk = 0; kk < 4; ++kk) {
            f32x4 z = {};
            z = __builtin_amdgcn_mfma_f32_16x16x32_bf16(kf0[kk], qf0, z, 0, 0, 0);
            z = __builtin_amdgcn_mfma_f32_16x16x32_bf16(kf1[kk], qf1, z, 0, 0, 0);
            sc[kk] = z;
        }
        // V^T fragments (A-operand): issue early, consumed after softmax
        s16x8 vfr[2][4];
        #pragma unroll
        for (int kk2 = 0; kk2 < 2; ++kk2)
            #pragma unroll
            for (int dt = 0; dt < 4; ++dt)
                vfr[kk2][dt] = *(const s16x8*)&vbfT[baseDS + (long)(dt * 16 + lc) * 2048 +
                                                   k0 + kk2 * 32 + lr * 8];
        // causal mask (diagonal tile): k = k0+kk*16+lr*4+i, q = q0w+lc
        if (kt == qt) {
            #pragma unroll
            for (int kk = 0; kk < 4; ++kk)
                #pragma unroll
                for (int i = 0; i < 4; ++i)
                    if (k0 + kk * 16 + lr * 4 + i > q0w + lc) sc[kk][i] = -INFINITY;
        }
        // row max: 16 in-register values + 2-shuffle cross-lane reduce over lr-group
        float mx = sc[0][0];
        #pragma unroll
        for (int kk = 0; kk < 4; ++kk)
            #pragma unroll
            for (int i = 0; i < 4; ++i) mx = fmaxf(mx, sc[kk][i]);
        mx = fmaxf(mx, __shfl_xor(mx, 16));
        mx = fmaxf(mx, __shfl_xor(mx, 32));
        // defer-max (T13): skip rescale if tile max within +8 of running max (p <= 2^8)
        if (!__all(mx <= m_ + 8.0f)) {
            float mn = fmaxf(m_, mx);
            float fac = __builtin_amdgcn_exp2f(m_ - mn);
            m_ = mn;
            lsum *= fac;
            #pragma unroll
            for (int dt = 0; dt < 4; ++dt)
                #pragma unroll
                for (int i = 0; i < 4; ++i) Oacc[dt][i] *= fac;
        }
        s16x4 pk[4];
        #pragma unroll
        for (int kk = 0; kk < 4; ++kk) {
            #pragma unroll
            for (int i = 0; i < 4; ++i) {
                float p = __builtin_amdgcn_exp2f(sc[kk][i] - m_);
                lsum += p;
                pk[kk][i] = f2bf(p);
            }
            *(s16x4*)&P[wv][lc][kk * 16 + lr * 4] = pk[kk];
        }
        // PV: O^T += V^T @ P^T   (per-wave LDS; same-wave ordering, no barrier)
        #pragma unroll
        for (int kk2 = 0; kk2 < 2; ++kk2) {
            s16x8 pf;
            *(s16x4*)&pf = *(const s16x4*)&P[wv][lc][kk2 * 32 + lr * 8];
            *(((s16x4*)&pf) + 1) = *(const s16x4*)&P[wv][lc][kk2 * 32 + lr * 8 + 4];
            #pragma unroll
            for (int dt = 0; dt < 4; ++dt)
                Oacc[dt] = __builtin_amdgcn_mfma_f32_16x16x32_bf16(vfr[kk2][dt], pf,
                                                                   Oacc[dt], 0, 0, 0);
        }
    }

    // epilogue: reduce partial lsum across lr-group, then O /= lsum; packed 8B stores
    lsum += __shfl_xor(lsum, 16);
    lsum += __shfl_xor(lsum, 32);
    const int b = bh >> 4, h = bh & 15;
    float inv = 1.0f / lsum;
    #pragma unroll
    for (int dt = 0; dt < 4; ++dt) {
        s16x4 o;
        #pragma unroll
        for (int i = 0; i < 4; ++i) o[i] = f2bf(Oacc[dt][i] * inv);
        *(s16x4*)&obf[(long)(b * 2048 + q0w + lc) * 1024 + h * 64 + dt * 16 + lr * 4] = o;
    }
}

// ---------------- launch ----------------

extern "C" void kernel_launch(void* const* d_in, const int* in_sizes, int n_in,
                              void* d_out, int out_size, void* d_ws, size_t ws_size,
                              hipStream_t stream) {
    const float* x = (const float*)d_in[0];
    const float* qkv_w = (const float*)d_in[1];
    const float* qkv_b = (const float*)d_in[2];
    const float* proj_w = (const float*)d_in[3];
    const float* proj_b = (const float*)d_in[4];

    float* out = (float*)d_out;
    float* kout = out + 4194304;
    float* vout = out + 8388608;

    short* x_bf = (short*)d_ws;           // 4194304 shorts
    short* wT1 = x_bf + 4194304;          // 3145728
    short* wT2 = wT1 + 3145728;           // 1048576
    short* q_bf = wT2 + 1048576;          // 4194304
    short* k_bf = q_bf + 4194304;         // 4194304
    short* vT_bf = k_bf + 4194304;        // 4194304 ([B,H,D,S])
    short* o_bf = x_bf;                   // alias: x_bf dead after GEMM1

    convert_f32_bf16<<<2048, 256, 0, stream>>>(x, x_bf, 4194304);
    transpose_conv<<<dim3(96, 32), dim3(32, 8), 0, stream>>>(qkv_w, wT1, 1024, 3072);
    transpose_conv<<<dim3(32, 32), dim3(32, 8), 0, stream>>>(proj_w, wT2, 1024, 1024);

    gemm_bf16<1><<<dim3(24, 32), 256, 0, stream>>>(x_bf, wT1, qkv_b, 4096, 3072, 1024,
                                                   nullptr, q_bf, k_bf, vT_bf, kout, vout);

    attn_kernel<<<512, 512, 0, stream>>>(q_bf, k_bf, vT_bf, o_bf);

    gemm_bf16<2><<<dim3(8, 32), 256, 0, stream>>>(o_bf, wT2, proj_b, 4096, 1024, 1024,
                                                  out, nullptr, nullptr, nullptr, nullptr, nullptr);
}